// Round 5
// baseline (249.275 us; speedup 1.0000x reference)
//
#include <hip/hip_runtime.h>

typedef int v4i __attribute__((ext_vector_type(4)));

#define KDIM 2048
#define NDIM 2048

#define GLOAD16(g, l) __builtin_amdgcn_global_load_lds(                      \
    (const __attribute__((address_space(1))) void*)(g),                      \
    (__attribute__((address_space(3))) void*)(l), 16, 0, 0)

// ---------------- quant kernels ----------------

__device__ __forceinline__ int pack4q(float4 v, float s) {
  int a = __float2int_rn(v.x * s);
  int b = __float2int_rn(v.y * s);
  int c = __float2int_rn(v.z * s);
  int d = __float2int_rn(v.w * s);
  a = max(-128, min(127, a)); b = max(-128, min(127, b));
  c = max(-128, min(127, c)); d = max(-128, min(127, d));
  return (a & 0xff) | ((b & 0xff) << 8) | ((c & 0xff) << 16) | ((d & 0xff) << 24);
}

__global__ __launch_bounds__(256) void quant_rows(const float* __restrict__ x,
                                                  signed char* __restrict__ q,
                                                  float* __restrict__ rscale) {
  const int row = blockIdx.x;
  const float4* xr = (const float4*)(x + (size_t)row * KDIM);
  float4 v0 = xr[threadIdx.x];
  float4 v1 = xr[256 + threadIdx.x];
  float m = fmaxf(fmaxf(fabsf(v0.x), fabsf(v0.y)), fmaxf(fabsf(v0.z), fabsf(v0.w)));
  m = fmaxf(m, fmaxf(fmaxf(fabsf(v1.x), fabsf(v1.y)), fmaxf(fabsf(v1.z), fabsf(v1.w))));
  #pragma unroll
  for (int off = 32; off > 0; off >>= 1) m = fmaxf(m, __shfl_xor(m, off));
  __shared__ float red[4];
  if ((threadIdx.x & 63) == 0) red[threadIdx.x >> 6] = m;
  __syncthreads();
  float xmax = fmaxf(fmaxf(red[0], red[1]), fmaxf(red[2], red[3]));
  xmax = fmaxf(xmax, 1e-5f);
  const float scale = 127.0f / xmax;
  int* qr = (int*)(q + (size_t)row * KDIM);
  qr[threadIdx.x] = pack4q(v0, scale);
  qr[256 + threadIdx.x] = pack4q(v1, scale);
  if (threadIdx.x == 0) rscale[row] = xmax * (1.0f / 127.0f);
}

__global__ __launch_bounds__(256) void quant_w(const float* __restrict__ W,
                                               signed char* __restrict__ Wq) {
  const int i = blockIdx.x * 256 + threadIdx.x;
  float4 v = ((const float4*)W)[i];
  int a = (int)v.x, b = (int)v.y, c = (int)v.z, d = (int)v.w;
  ((int*)Wq)[i] = (a & 0xff) | ((b & 0xff) << 8) | ((c & 0xff) << 16) | ((d & 0xff) << 24);
}

// ---------------- 256x256 8-wave i8 GEMM, 4-deep LDS ring, counted vmcnt ----------------
// Round-4 change: ONE phase + ONE barrier per K-tile (was 2 phases / 4 barriers).
// All 12 fragment ds_reads are compiler-tracked (no asm lgkmcnt, no sched_barrier
// pins) so the LDS read burst overlaps under the 32-MFMA cluster instead of
// serializing between barriers. Ring depth / vmcnt ladder unchanged:
// boundary end-of-tile-t: vmcnt(8) waits S(t+1) (needed by tile t+1's reads).
// LDS swizzle (conflict-free, verified round 4: SQ_LDS_BANK_CONFLICT = 0):
// physical 16B slot = logical slot ^ ((row>>1)&3), applied on global source
// (global_load_lds dest is linear) and on ds_read addresses.

#define VM8 asm volatile("s_waitcnt vmcnt(8)" ::: "memory")
#define VM4 asm volatile("s_waitcnt vmcnt(4)" ::: "memory")
#define VM0 asm volatile("s_waitcnt vmcnt(0)" ::: "memory")
#define VMNONE

#define STAGE_A(U, T)                                                        \
  GLOAD16(sa + (T) * 64, lds + (U) * 32768 + dstw);                          \
  GLOAD16(sa + (T) * 64 + 128 * KDIM, lds + (U) * 32768 + 8192 + dstw);
#define STAGE_B(U, T)                                                        \
  GLOAD16(sb + (T) * 64, lds + (U) * 32768 + 16384 + dstw);                  \
  GLOAD16(sb + (T) * 64 + 128 * KDIM, lds + (U) * 32768 + 24576 + dstw);

#define MF(m, n, a) acc[m][n] = __builtin_amdgcn_mfma_i32_16x16x64_i8((a), bf[n], acc[m][n], 0, 0, 0);

#define KTILE(U, T, DOSTAGE, VMEND)                                          \
  {                                                                          \
    /* fragment reads: B first so MF(0,*) is ready after 5 loads */          \
    bf[0] = *(const v4i*)(lds + (U) * 32768 + bRd);                          \
    bf[1] = *(const v4i*)(lds + (U) * 32768 + bRd + 1024);                   \
    bf[2] = *(const v4i*)(lds + (U) * 32768 + bRd + 2048);                   \
    bf[3] = *(const v4i*)(lds + (U) * 32768 + bRd + 3072);                   \
    v4i a0 = *(const v4i*)(lds + (U) * 32768 + aRd);                         \
    v4i a1 = *(const v4i*)(lds + (U) * 32768 + aRd + 1024);                  \
    v4i a2 = *(const v4i*)(lds + (U) * 32768 + aRd + 2048);                  \
    v4i a3 = *(const v4i*)(lds + (U) * 32768 + aRd + 3072);                  \
    v4i a4 = *(const v4i*)(lds + (U) * 32768 + aRd + 4096);                  \
    v4i a5 = *(const v4i*)(lds + (U) * 32768 + aRd + 5120);                  \
    v4i a6 = *(const v4i*)(lds + (U) * 32768 + aRd + 6144);                  \
    v4i a7 = *(const v4i*)(lds + (U) * 32768 + aRd + 7168);                  \
    if (DOSTAGE) {                                                           \
      STAGE_A((((U) + 3) & 3), (T) + 3)                                      \
      STAGE_B((((U) + 3) & 3), (T) + 3)                                      \
    }                                                                        \
    __builtin_amdgcn_s_setprio(1);                                           \
    MF(0, 0, a0) MF(0, 1, a0) MF(0, 2, a0) MF(0, 3, a0)                      \
    MF(1, 0, a1) MF(1, 1, a1) MF(1, 2, a1) MF(1, 3, a1)                      \
    MF(2, 0, a2) MF(2, 1, a2) MF(2, 2, a2) MF(2, 3, a2)                      \
    MF(3, 0, a3) MF(3, 1, a3) MF(3, 2, a3) MF(3, 3, a3)                      \
    MF(4, 0, a4) MF(4, 1, a4) MF(4, 2, a4) MF(4, 3, a4)                      \
    MF(5, 0, a5) MF(5, 1, a5) MF(5, 2, a5) MF(5, 3, a5)                      \
    MF(6, 0, a6) MF(6, 1, a6) MF(6, 2, a6) MF(6, 3, a6)                      \
    MF(7, 0, a7) MF(7, 1, a7) MF(7, 2, a7) MF(7, 3, a7)                      \
    __builtin_amdgcn_s_setprio(0);                                           \
    VMEND;                                                                   \
    __builtin_amdgcn_s_barrier();                                            \
  }

__global__ __launch_bounds__(512, 2) void gemm_i8(const signed char* __restrict__ A,
                                                  const signed char* __restrict__ B,
                                                  const float* __restrict__ rscale,
                                                  float* __restrict__ C) {
  __shared__ __align__(16) signed char lds[131072];
  const int bid = blockIdx.x;
  const int lid = (bid & 7) * 128 + (bid >> 3);  // bijective XCD swizzle (1024 % 8 == 0)
  const int bm = lid >> 3;                       // 128 row tiles
  const int bn = lid & 7;                        // 8 col tiles
  const int tid = threadIdx.x;
  const int wid = tid >> 6;
  const int lane = tid & 63;
  const int wr = wid >> 2, wc = wid & 3;

  // staging: per call, thread covers row = wid*16 + (lane>>2) (within a 128-row half),
  // physical dest slot = lane&3 (HW linear: base + lane*16).
  // source logical slot = (lane&3) ^ ((row>>1)&3) = (lane&3) ^ ((lane>>3)&3).
  const int srow = wid * 16 + (lane >> 2);
  const int scol = (((lane & 3) ^ ((lane >> 3) & 3)) << 4);
  const signed char* sa = A + (size_t)(bm * 256 + srow) * KDIM + scol;
  const signed char* sb = B + (size_t)(bn * 256 + srow) * KDIM + scol;
  const int dstw = wid << 10;  // wave-uniform LDS chunk; HW adds lane*16

  // ds_read: logical k-slot = lane>>4, row = ...+(lane&15) -> physical slot
  // = (lane>>4) ^ ((lane>>1)&3).
  const int rslot = (((lane >> 4) ^ ((lane >> 1) & 3)) << 4);
  const int aRd = (wr * 128 + (lane & 15)) * 64 + rslot;
  const int bRd = 16384 + (wc * 64 + (lane & 15)) * 64 + rslot;

  v4i acc[8][4] = {};
  v4i bf[4];

  // prologue: stage S(0), S(1), S(2); wait S(0)
  STAGE_A(0, 0) STAGE_B(0, 0)
  STAGE_A(1, 1) STAGE_B(1, 1)
  STAGE_A(2, 2) STAGE_B(2, 2)
  VM8;
  __builtin_amdgcn_s_barrier();

  for (int ti = 0; ti < 7; ++ti) {
    const int t = ti * 4;
    KTILE(0, t + 0, 1, VM8)
    KTILE(1, t + 1, 1, VM8)
    KTILE(2, t + 2, 1, VM8)
    KTILE(3, t + 3, 1, VM8)
  }
  KTILE(0, 28, 1, VM8)    // stages S(31)
  KTILE(1, 29, 0, VM4)    // waits S(30)
  KTILE(2, 30, 0, VM0)    // waits S(31)
  KTILE(3, 31, 0, VMNONE)

  // epilogue: C/D layout col = lane&15, row = (lane>>4)*4 + reg
  const int col0 = bn * 256 + wc * 64 + (lane & 15);
  const int rbase = bm * 256 + wr * 128 + ((lane >> 4) << 2);
  #pragma unroll
  for (int m = 0; m < 8; ++m) {
    #pragma unroll
    for (int r = 0; r < 4; ++r) {
      const int row = rbase + m * 16 + r;
      const float s = rscale[row];
      float* crow = C + (size_t)row * NDIM + col0;
      #pragma unroll
      for (int n = 0; n < 4; ++n) crow[n * 16] = (float)acc[m][n][r] * s;
    }
  }
}

extern "C" void kernel_launch(void* const* d_in, const int* in_sizes, int n_in,
                              void* d_out, int out_size, void* d_ws, size_t ws_size,
                              hipStream_t stream) {
  const float* x = (const float*)d_in[0];
  const float* W = (const float*)d_in[1];
  float* out = (float*)d_out;
  const int M = in_sizes[0] / KDIM;  // 32768

  signed char* q = (signed char*)d_ws;                       // M*K   = 64 MB
  signed char* Wq = q + (size_t)M * KDIM;                    // N*K   =  4 MB
  float* rscale = (float*)(Wq + (size_t)NDIM * KDIM);        // M*4   = 128 KB

  quant_rows<<<M, 256, 0, stream>>>(x, q, rscale);
  quant_w<<<(NDIM * KDIM / 4) / 256, 256, 0, stream>>>(W, Wq);
  gemm_i8<<<(M / 256) * (NDIM / 256), 512, 0, stream>>>(q, Wq, rscale, out);
}

// Round 6
// 240.437 us; speedup vs baseline: 1.0368x; 1.0368x over previous
//
#include <hip/hip_runtime.h>

typedef int v4i __attribute__((ext_vector_type(4)));

#define KDIM 2048
#define NDIM 2048

#define GLOAD16(g, l) __builtin_amdgcn_global_load_lds(                      \
    (const __attribute__((address_space(1))) void*)(g),                      \
    (__attribute__((address_space(3))) void*)(l), 16, 0, 0)

// ---------------- quant kernels ----------------

__device__ __forceinline__ int pack4q(float4 v, float s) {
  int a = __float2int_rn(v.x * s);
  int b = __float2int_rn(v.y * s);
  int c = __float2int_rn(v.z * s);
  int d = __float2int_rn(v.w * s);
  a = max(-128, min(127, a)); b = max(-128, min(127, b));
  c = max(-128, min(127, c)); d = max(-128, min(127, d));
  return (a & 0xff) | ((b & 0xff) << 8) | ((c & 0xff) << 16) | ((d & 0xff) << 24);
}

__global__ __launch_bounds__(256) void quant_rows(const float* __restrict__ x,
                                                  signed char* __restrict__ q,
                                                  float* __restrict__ rscale) {
  const int row = blockIdx.x;
  const float4* xr = (const float4*)(x + (size_t)row * KDIM);
  float4 v0 = xr[threadIdx.x];
  float4 v1 = xr[256 + threadIdx.x];
  float m = fmaxf(fmaxf(fabsf(v0.x), fabsf(v0.y)), fmaxf(fabsf(v0.z), fabsf(v0.w)));
  m = fmaxf(m, fmaxf(fmaxf(fabsf(v1.x), fabsf(v1.y)), fmaxf(fabsf(v1.z), fabsf(v1.w))));
  #pragma unroll
  for (int off = 32; off > 0; off >>= 1) m = fmaxf(m, __shfl_xor(m, off));
  __shared__ float red[4];
  if ((threadIdx.x & 63) == 0) red[threadIdx.x >> 6] = m;
  __syncthreads();
  float xmax = fmaxf(fmaxf(red[0], red[1]), fmaxf(red[2], red[3]));
  xmax = fmaxf(xmax, 1e-5f);
  const float scale = 127.0f / xmax;
  int* qr = (int*)(q + (size_t)row * KDIM);
  qr[threadIdx.x] = pack4q(v0, scale);
  qr[256 + threadIdx.x] = pack4q(v1, scale);
  if (threadIdx.x == 0) rscale[row] = xmax * (1.0f / 127.0f);
}

__global__ __launch_bounds__(256) void quant_w(const float* __restrict__ W,
                                               signed char* __restrict__ Wq) {
  const int i = blockIdx.x * 256 + threadIdx.x;
  float4 v = ((const float4*)W)[i];
  int a = (int)v.x, b = (int)v.y, c = (int)v.z, d = (int)v.w;
  ((int*)Wq)[i] = (a & 0xff) | ((b & 0xff) << 8) | ((c & 0xff) << 16) | ((d & 0xff) << 24);
}

// ---- 256x256 8-wave i8 GEMM, 4-deep ring, counted vmcnt, REGISTER-PIPELINED frags ----
// Round-5 change: during tile t the MFMA cluster consumes frag set CUR (read during
// tile t-1) while the 12 ds_reads for tile t+1 fill set NXT. MFMA has no dependency
// on in-flight reads -> LDS burst hides under MFMA issue window. One barrier/tile.
// Boundary wait: vmcnt(4) => S(t+2) complete (its frags are read during tile t+1).
// LDS swizzle (verified conflict-free): physical 16B slot = logical ^ ((row>>1)&3),
// applied on global source (global_load_lds dest linear) and ds_read addrs.

#define VM4 asm volatile("s_waitcnt vmcnt(4)" ::: "memory")
#define VM0 asm volatile("s_waitcnt vmcnt(0)" ::: "memory")
#define VMNONE

#define STAGE_AB(U, T)                                                       \
  GLOAD16(sa + (T) * 64, lds + (U) * 32768 + dstw);                          \
  GLOAD16(sa + (T) * 64 + 128 * KDIM, lds + (U) * 32768 + 8192 + dstw);      \
  GLOAD16(sb + (T) * 64, lds + (U) * 32768 + 16384 + dstw);                  \
  GLOAD16(sb + (T) * 64 + 128 * KDIM, lds + (U) * 32768 + 24576 + dstw);

#define DECLSET(P) v4i P##b0, P##b1, P##b2, P##b3,                           \
                       P##a0, P##a1, P##a2, P##a3, P##a4, P##a5, P##a6, P##a7;

#define READSET(U, P)                                                        \
  P##b0 = *(const v4i*)(lds + (U) * 32768 + bRd);                            \
  P##b1 = *(const v4i*)(lds + (U) * 32768 + bRd + 1024);                     \
  P##b2 = *(const v4i*)(lds + (U) * 32768 + bRd + 2048);                     \
  P##b3 = *(const v4i*)(lds + (U) * 32768 + bRd + 3072);                     \
  P##a0 = *(const v4i*)(lds + (U) * 32768 + aRd);                            \
  P##a1 = *(const v4i*)(lds + (U) * 32768 + aRd + 1024);                     \
  P##a2 = *(const v4i*)(lds + (U) * 32768 + aRd + 2048);                     \
  P##a3 = *(const v4i*)(lds + (U) * 32768 + aRd + 3072);                     \
  P##a4 = *(const v4i*)(lds + (U) * 32768 + aRd + 4096);                     \
  P##a5 = *(const v4i*)(lds + (U) * 32768 + aRd + 5120);                     \
  P##a6 = *(const v4i*)(lds + (U) * 32768 + aRd + 6144);                     \
  P##a7 = *(const v4i*)(lds + (U) * 32768 + aRd + 7168);

#define MF1(m, n, A, BF) acc[m][n] = __builtin_amdgcn_mfma_i32_16x16x64_i8((A), (BF), acc[m][n], 0, 0, 0);
#define MFROW(m, A, P)                                                       \
  MF1(m, 0, A, P##b0) MF1(m, 1, A, P##b1) MF1(m, 2, A, P##b2) MF1(m, 3, A, P##b3)
#define MFSET(P)                                                             \
  __builtin_amdgcn_s_setprio(1);                                             \
  MFROW(0, P##a0, P) MFROW(1, P##a1, P) MFROW(2, P##a2, P)                   \
  MFROW(3, P##a3, P) MFROW(4, P##a4, P) MFROW(5, P##a5, P)                   \
  MFROW(6, P##a6, P) MFROW(7, P##a7, P)                                      \
  __builtin_amdgcn_s_setprio(0);

// Tile t: U = t&3 (buffer being consumed via set CUR), reads fill NXT from (U+1)&3,
// stage fills (U+3)&3 with K-tile T+3.
#define KTILE(U, T, CUR, NXT, DOREAD, DOSTAGE, VMEND)                        \
  {                                                                          \
    if (DOREAD) { READSET((((U) + 1) & 3), NXT) }                            \
    if (DOSTAGE) { STAGE_AB((((U) + 3) & 3), (T) + 3) }                      \
    __builtin_amdgcn_sched_barrier(0);  /* reads+stage issue before MFMA */  \
    MFSET(CUR)                                                               \
    __builtin_amdgcn_sched_barrier(0);                                       \
    VMEND;                                                                   \
    __builtin_amdgcn_s_barrier();                                            \
    __builtin_amdgcn_sched_barrier(0);  /* no hoist above barrier */         \
  }

__global__ __launch_bounds__(512, 2) void gemm_i8(const signed char* __restrict__ A,
                                                  const signed char* __restrict__ B,
                                                  const float* __restrict__ rscale,
                                                  float* __restrict__ C) {
  __shared__ __align__(16) signed char lds[131072];
  const int bid = blockIdx.x;
  const int lid = (bid & 7) * 128 + (bid >> 3);  // bijective XCD swizzle (1024 % 8 == 0)
  const int bm = lid >> 3;                       // 128 row tiles
  const int bn = lid & 7;                        // 8 col tiles
  const int tid = threadIdx.x;
  const int wid = tid >> 6;
  const int lane = tid & 63;
  const int wr = wid >> 2, wc = wid & 3;

  // staging: thread covers row = wid*16 + (lane>>2) (within each 128-row half),
  // dest slot = lane&3 (HW linear). Source logical slot = (lane&3) ^ ((row>>1)&3).
  const int srow = wid * 16 + (lane >> 2);
  const int scol = (((lane & 3) ^ ((lane >> 3) & 3)) << 4);
  const signed char* sa = A + (size_t)(bm * 256 + srow) * KDIM + scol;
  const signed char* sb = B + (size_t)(bn * 256 + srow) * KDIM + scol;
  const int dstw = wid << 10;  // wave-uniform LDS chunk; HW adds lane*16

  // ds_read: logical k-slot = lane>>4, row = ...+(lane&15) -> physical slot
  // = (lane>>4) ^ ((lane>>1)&3).
  const int rslot = (((lane >> 4) ^ ((lane >> 1) & 3)) << 4);
  const int aRd = (wr * 128 + (lane & 15)) * 64 + rslot;
  const int bRd = 16384 + (wc * 64 + (lane & 15)) * 64 + rslot;

  v4i acc[8][4] = {};
  DECLSET(fX) DECLSET(fY)

  // prologue: stage S(0),S(1),S(2); wait S(0),S(1) (leave S(2) in flight); read frags(0).
  STAGE_AB(0, 0)
  STAGE_AB(1, 1)
  STAGE_AB(2, 2)
  VM4;
  __builtin_amdgcn_s_barrier();
  __builtin_amdgcn_sched_barrier(0);
  READSET(0, fX)

  // tiles 0..27: full pipeline. CUR/NXT alternate X,Y per tile; U = t&3.
  for (int ti = 0; ti < 7; ++ti) {
    const int t = ti * 4;
    KTILE(0, t + 0, fX, fY, 1, 1, VM4)
    KTILE(1, t + 1, fY, fX, 1, 1, VM4)
    KTILE(2, t + 2, fX, fY, 1, 1, VM4)
    KTILE(3, t + 3, fY, fX, 1, 1, VM4)
  }
  // tails: t=28 stages S(31) then waits S(30); t=29 waits S(31); t=30/31 drain.
  KTILE(0, 28, fX, fY, 1, 1, VM4)
  KTILE(1, 29, fY, fX, 1, 0, VM0)
  KTILE(2, 30, fX, fY, 1, 0, VMNONE)
  KTILE(3, 31, fY, fX, 0, 0, VMNONE)

  // epilogue: C/D layout col = lane&15, row = (lane>>4)*4 + reg
  const int col0 = bn * 256 + wc * 64 + (lane & 15);
  const int rbase = bm * 256 + wr * 128 + ((lane >> 4) << 2);
  #pragma unroll
  for (int m = 0; m < 8; ++m) {
    #pragma unroll
    for (int r = 0; r < 4; ++r) {
      const int row = rbase + m * 16 + r;
      const float s = rscale[row];
      float* crow = C + (size_t)row * NDIM + col0;
      #pragma unroll
      for (int n = 0; n < 4; ++n) crow[n * 16] = (float)acc[m][n][r] * s;
    }
  }
}

extern "C" void kernel_launch(void* const* d_in, const int* in_sizes, int n_in,
                              void* d_out, int out_size, void* d_ws, size_t ws_size,
                              hipStream_t stream) {
  const float* x = (const float*)d_in[0];
  const float* W = (const float*)d_in[1];
  float* out = (float*)d_out;
  const int M = in_sizes[0] / KDIM;  // 32768

  signed char* q = (signed char*)d_ws;                       // M*K   = 64 MB
  signed char* Wq = q + (size_t)M * KDIM;                    // N*K   =  4 MB
  float* rscale = (float*)(Wq + (size_t)NDIM * KDIM);        // M*4   = 128 KB

  quant_rows<<<M, 256, 0, stream>>>(x, q, rscale);
  quant_w<<<(NDIM * KDIM / 4) / 256, 256, 0, stream>>>(W, Wq);
  gemm_i8<<<(M / 256) * (NDIM / 256), 512, 0, stream>>>(q, Wq, rscale, out);
}

// Round 7
// 238.077 us; speedup vs baseline: 1.0470x; 1.0099x over previous
//
#include <hip/hip_runtime.h>

typedef int v4i __attribute__((ext_vector_type(4)));

#define KDIM 2048
#define NDIM 2048

#define GLOAD16(g, l) __builtin_amdgcn_global_load_lds(                      \
    (const __attribute__((address_space(1))) void*)(g),                      \
    (__attribute__((address_space(3))) void*)(l), 16, 0, 0)

// ---------------- quant kernels ----------------

__device__ __forceinline__ int pack4q(float4 v, float s) {
  int a = __float2int_rn(v.x * s);
  int b = __float2int_rn(v.y * s);
  int c = __float2int_rn(v.z * s);
  int d = __float2int_rn(v.w * s);
  a = max(-128, min(127, a)); b = max(-128, min(127, b));
  c = max(-128, min(127, c)); d = max(-128, min(127, d));
  return (a & 0xff) | ((b & 0xff) << 8) | ((c & 0xff) << 16) | ((d & 0xff) << 24);
}

__global__ __launch_bounds__(256) void quant_rows(const float* __restrict__ x,
                                                  signed char* __restrict__ q,
                                                  float* __restrict__ rscale) {
  const int row = blockIdx.x;
  const float4* xr = (const float4*)(x + (size_t)row * KDIM);
  float4 v0 = xr[threadIdx.x];
  float4 v1 = xr[256 + threadIdx.x];
  float m = fmaxf(fmaxf(fabsf(v0.x), fabsf(v0.y)), fmaxf(fabsf(v0.z), fabsf(v0.w)));
  m = fmaxf(m, fmaxf(fmaxf(fabsf(v1.x), fabsf(v1.y)), fmaxf(fabsf(v1.z), fabsf(v1.w))));
  #pragma unroll
  for (int off = 32; off > 0; off >>= 1) m = fmaxf(m, __shfl_xor(m, off));
  __shared__ float red[4];
  if ((threadIdx.x & 63) == 0) red[threadIdx.x >> 6] = m;
  __syncthreads();
  float xmax = fmaxf(fmaxf(red[0], red[1]), fmaxf(red[2], red[3]));
  xmax = fmaxf(xmax, 1e-5f);
  const float scale = 127.0f / xmax;
  int* qr = (int*)(q + (size_t)row * KDIM);
  qr[threadIdx.x] = pack4q(v0, scale);
  qr[256 + threadIdx.x] = pack4q(v1, scale);
  if (threadIdx.x == 0) rscale[row] = xmax * (1.0f / 127.0f);
}

__global__ __launch_bounds__(256) void quant_w(const float* __restrict__ W,
                                               signed char* __restrict__ Wq) {
  const int i = blockIdx.x * 256 + threadIdx.x;
  float4 v = ((const float4*)W)[i];
  int a = (int)v.x, b = (int)v.y, c = (int)v.z, d = (int)v.w;
  ((int*)Wq)[i] = (a & 0xff) | ((b & 0xff) << 8) | ((c & 0xff) << 16) | ((d & 0xff) << 24);
}

// ---- 128x256 4-wave i8 GEMM, ring depth 3 (72 KB LDS -> 2 blocks/CU), counted vmcnt ----
// Round-6 change: TWO independent blocks per CU (two barrier groups) so that when one
// block's waves sit in lgkmcnt/barrier, the sibling block's waves feed the MFMA pipe
// (m114 cross-wave overlap). Wave-tile 64x128 keeps reads:MFMA = 12:32 = 0.375.
// Ladder: tile t stages S(t+2) (6 gloads); end-of-tile vmcnt(6) waits S(t+1) only
// (never drains in main loop); VM0 only at t=30.
// LDS swizzle (verified conflict-free R4): physical 16B slot = logical ^ ((row>>1)&3),
// applied on global source (global_load_lds dest is linear) and on ds_read addrs.

#define VM6 asm volatile("s_waitcnt vmcnt(6)" ::: "memory")
#define VM0 asm volatile("s_waitcnt vmcnt(0)" ::: "memory")
#define VMNONE

// ring buffer stride 24576: A[128][64] at +0 (8 KB), B[256][64] at +8192 (16 KB)
#define STAGE(U, T)                                                          \
  GLOAD16(sa + (T) * 64,             lds + (U) * 24576 + dstw);              \
  GLOAD16(sa + (T) * 64 + 64 * KDIM, lds + (U) * 24576 + 4096 + dstw);       \
  GLOAD16(sb + (T) * 64,             lds + (U) * 24576 + 8192 + dstw);       \
  GLOAD16(sb + (T) * 64 + 64 * KDIM, lds + (U) * 24576 + 12288 + dstw);      \
  GLOAD16(sb + (T) * 64 + 128 * KDIM, lds + (U) * 24576 + 16384 + dstw);     \
  GLOAD16(sb + (T) * 64 + 192 * KDIM, lds + (U) * 24576 + 20480 + dstw);

#define MF1(m, n, A, BF) acc[m][n] = __builtin_amdgcn_mfma_i32_16x16x64_i8((A), (BF), acc[m][n], 0, 0, 0);

#define KTILE(U, T, DOSTAGE, VMEND)                                          \
  {                                                                          \
    if (DOSTAGE) { STAGE((((U) + 2) % 3), (T) + 2) }                         \
    v4i b0 = *(const v4i*)(lds + (U) * 24576 + bRd);                         \
    v4i b1 = *(const v4i*)(lds + (U) * 24576 + bRd + 1024);                  \
    v4i b2 = *(const v4i*)(lds + (U) * 24576 + bRd + 2048);                  \
    v4i b3 = *(const v4i*)(lds + (U) * 24576 + bRd + 3072);                  \
    v4i b4 = *(const v4i*)(lds + (U) * 24576 + bRd + 4096);                  \
    v4i b5 = *(const v4i*)(lds + (U) * 24576 + bRd + 5120);                  \
    v4i b6 = *(const v4i*)(lds + (U) * 24576 + bRd + 6144);                  \
    v4i b7 = *(const v4i*)(lds + (U) * 24576 + bRd + 7168);                  \
    v4i a0 = *(const v4i*)(lds + (U) * 24576 + aRd);                         \
    v4i a1 = *(const v4i*)(lds + (U) * 24576 + aRd + 1024);                  \
    v4i a2 = *(const v4i*)(lds + (U) * 24576 + aRd + 2048);                  \
    v4i a3 = *(const v4i*)(lds + (U) * 24576 + aRd + 3072);                  \
    __builtin_amdgcn_s_setprio(1);                                           \
    MF1(0, 0, a0, b0) MF1(0, 1, a0, b1) MF1(0, 2, a0, b2) MF1(0, 3, a0, b3)  \
    MF1(0, 4, a0, b4) MF1(0, 5, a0, b5) MF1(0, 6, a0, b6) MF1(0, 7, a0, b7)  \
    MF1(1, 0, a1, b0) MF1(1, 1, a1, b1) MF1(1, 2, a1, b2) MF1(1, 3, a1, b3)  \
    MF1(1, 4, a1, b4) MF1(1, 5, a1, b5) MF1(1, 6, a1, b6) MF1(1, 7, a1, b7)  \
    MF1(2, 0, a2, b0) MF1(2, 1, a2, b1) MF1(2, 2, a2, b2) MF1(2, 3, a2, b3)  \
    MF1(2, 4, a2, b4) MF1(2, 5, a2, b5) MF1(2, 6, a2, b6) MF1(2, 7, a2, b7)  \
    MF1(3, 0, a3, b0) MF1(3, 1, a3, b1) MF1(3, 2, a3, b2) MF1(3, 3, a3, b3)  \
    MF1(3, 4, a3, b4) MF1(3, 5, a3, b5) MF1(3, 6, a3, b6) MF1(3, 7, a3, b7)  \
    __builtin_amdgcn_s_setprio(0);                                           \
    VMEND;                                                                   \
    __builtin_amdgcn_s_barrier();                                            \
    __builtin_amdgcn_sched_barrier(0);                                       \
  }

__global__ __launch_bounds__(256, 2) void gemm_i8(const signed char* __restrict__ A,
                                                  const signed char* __restrict__ B,
                                                  const float* __restrict__ rscale,
                                                  float* __restrict__ C) {
  __shared__ __align__(16) signed char lds[3 * 24576];  // 72 KB -> 2 blocks/CU
  const int bid = blockIdx.x;
  const int lid = (bid & 7) * 256 + (bid >> 3);  // bijective XCD swizzle (2048 % 8 == 0)
  const int bm = lid >> 3;                       // 256 row tiles (M/128)
  const int bn = lid & 7;                        // 8 col tiles (N/256)
  const int tid = threadIdx.x;
  const int wid = tid >> 6;
  const int lane = tid & 63;
  const int wr = wid >> 1, wc = wid & 1;         // wave-tile 64 rows x 128 cols

  // staging: per gload round, thread covers row = base + wid*16 + (lane>>2),
  // dest slot = lane&3 (HW linear: base + lane*16).
  // source logical slot = (lane&3) ^ ((row>>1)&3) = (lane&3) ^ ((lane>>3)&3).
  const int srow = wid * 16 + (lane >> 2);
  const int scol = (((lane & 3) ^ ((lane >> 3) & 3)) << 4);
  const signed char* sa = A + (size_t)(bm * 128 + srow) * KDIM + scol;
  const signed char* sb = B + (size_t)(bn * 256 + srow) * KDIM + scol;
  const int dstw = wid << 10;  // wave-uniform LDS chunk; HW adds lane*16

  // ds_read: logical k-slot = lane>>4, row = ...+(lane&15) -> physical slot
  // = (lane>>4) ^ ((lane>>1)&3).
  const int rslot = (((lane >> 4) ^ ((lane >> 1) & 3)) << 4);
  const int aRd = (wr * 64 + (lane & 15)) * 64 + rslot;
  const int bRd = 8192 + (wc * 128 + (lane & 15)) * 64 + rslot;

  v4i acc[4][8] = {};

  // prologue: stage S(0), S(1); wait S(0) (vmcnt(6) leaves S(1) in flight)
  STAGE(0, 0)
  STAGE(1, 1)
  VM6;
  __builtin_amdgcn_s_barrier();
  __builtin_amdgcn_sched_barrier(0);

  // 32 K-tiles, ring mod 3
  for (int ti = 0; ti < 10; ++ti) {
    const int t = ti * 3;
    KTILE(0, t + 0, 1, VM6)
    KTILE(1, t + 1, 1, VM6)
    KTILE(2, t + 2, 1, VM6)
  }
  KTILE(0, 30, 0, VM0)     // waits S(31)
  KTILE(1, 31, 0, VMNONE)

  // epilogue: C/D layout col = lane&15, row = (lane>>4)*4 + reg
  const int col0 = bn * 256 + wc * 128 + (lane & 15);
  const int rbase = bm * 128 + wr * 64 + ((lane >> 4) << 2);
  #pragma unroll
  for (int m = 0; m < 4; ++m) {
    #pragma unroll
    for (int r = 0; r < 4; ++r) {
      const int row = rbase + m * 16 + r;
      const float s = rscale[row];
      float* crow = C + (size_t)row * NDIM + col0;
      #pragma unroll
      for (int n = 0; n < 8; ++n) crow[n * 16] = (float)acc[m][n][r] * s;
    }
  }
}

extern "C" void kernel_launch(void* const* d_in, const int* in_sizes, int n_in,
                              void* d_out, int out_size, void* d_ws, size_t ws_size,
                              hipStream_t stream) {
  const float* x = (const float*)d_in[0];
  const float* W = (const float*)d_in[1];
  float* out = (float*)d_out;
  const int M = in_sizes[0] / KDIM;  // 32768

  signed char* q = (signed char*)d_ws;                       // M*K   = 64 MB
  signed char* Wq = q + (size_t)M * KDIM;                    // N*K   =  4 MB
  float* rscale = (float*)(Wq + (size_t)NDIM * KDIM);        // M*4   = 128 KB

  quant_rows<<<M, 256, 0, stream>>>(x, q, rscale);
  quant_w<<<(NDIM * KDIM / 4) / 256, 256, 0, stream>>>(W, Wq);
  gemm_i8<<<(M / 128) * (NDIM / 256), 256, 0, stream>>>(q, Wq, rscale, out);
}